// Round 2
// baseline (2826.612 us; speedup 1.0000x reference)
//
#include <hip/hip_runtime.h>

typedef __attribute__((ext_vector_type(4))) float f32x4;
typedef __attribute__((ext_vector_type(8))) short s16x8;
typedef __attribute__((ext_vector_type(8))) unsigned short u16x8;

#define TOKS_PER_B 50176   // 224*224
#define CDIM 384

// workspace region per (window, head): Q[49][96] | K[49][96] | Vt[96][64]
#define REG_HW   15552     // 4704 + 4704 + 6144 halfwords
#define QOFF     0
#define KOFF     4704
#define VTOFF    9408

__device__ __forceinline__ unsigned short f2bf(float f) {
  unsigned u = __builtin_bit_cast(unsigned, f);
  u += 0x7FFFu + ((u >> 16) & 1u);
  return (unsigned short)(u >> 16);
}
__device__ __forceinline__ unsigned cvt_pk(float lo, float hi) {
  unsigned r;
  asm("v_cvt_pk_bf16_f32 %0, %1, %2" : "=v"(r) : "v"(lo), "v"(hi));
  return r;
}

// ---------------- K0: zero the Vt pos-padding (49..63) once per launch ----------------
__global__ __launch_bounds__(256) void pad_zero(unsigned short* __restrict__ ws, int total) {
  const int i = blockIdx.x * 256 + threadIdx.x;
  if (i >= total) return;
  const int reg = i / 96, d = i - reg * 96;
  unsigned short* p = ws + (size_t)reg * REG_HW + VTOFF + d * 64 + 49;
  p[0] = 0;
  unsigned* q = (unsigned*)(p + 1);   // hw 50..63, 4B-aligned
  #pragma unroll
  for (int j = 0; j < 7; ++j) q[j] = 0;
}

// ---------------- K1: qkv GEMM -> blocked per-(window,head) workspace ----------------
// 1D grid = 9 * (toks/128), XCD-swizzled; block 256 (4 waves), wave -> 64x64 subtile.
// LDS [128][32] bf16 tiles. Swizzle (write == read):
//   element (row,k): chunk c=k>>3 stored at chunk c^((row>>2)&3), and row' = row^((row>>4)&1).
// Gives full 16 bank-pair coverage for the b64 writes and min-phase b128 reads (derived+checked).
__global__ __launch_bounds__(256) void qkv_gemm(
    const float* __restrict__ x, const float* __restrict__ wq,
    const float* __restrict__ bias, unsigned short* __restrict__ ws,
    long long t_base, int nwg) {
  __shared__ unsigned short As[128][32];   // 8 KB
  __shared__ unsigned short Bs[128][32];   // 8 KB
  const int tid  = threadIdx.x;
  const int lane = tid & 63, wv = tid >> 6;

  // bijective XCD swizzle (m204)
  const int qq  = nwg >> 3, rr = nwg & 7;
  const int xcd = blockIdx.x & 7, posb = blockIdx.x >> 3;
  const int wgid = (xcd < rr ? xcd * (qq + 1) : rr * (qq + 1) + (xcd - rr) * qq) + posb;
  const int nb = wgid % 9, mb = wgid / 9;   // n fastest: 9 blocks share one A-tile

  const long long t0 = t_base + (long long)mb * 128;
  const int b    = (int)(t0 / TOKS_PER_B);
  const int off0 = (int)(t0 - (long long)b * TOKS_PER_B);
  const float* xb = x + (size_t)b * CDIM * TOKS_PER_B + off0;
  const int n0 = nb * 128;
  const int ml = lane & 15, quad = lane >> 4;
  const int m_base = (wv & 1) * 64, n_base = (wv >> 1) * 64;

  // ---- A staging: thread -> tokens 4m..4m+3, k = 4kq..4kq+3 (4x float4 along tokens)
  const int am   = tid & 31;        // m
  const int akq  = tid >> 5;        // 0..7
  const int atok = am * 4;
  const int aswr = (am >> 2) & 1;                               // row' = row ^ aswr
  const int awoff = (((akq >> 1) ^ (am & 3)) << 3) + (akq & 1) * 4;
  const float* apk = xb + (size_t)(akq * 4) * TOKS_PER_B + atok;

  // ---- B staging: thread -> oc rows bn+32p, k cols bk4..bk4+3 (float4 along k)
  const int bk4  = (tid & 7) * 4;
  const int bn   = tid >> 3;
  const int bswr = (bn >> 4) & 1;
  const int bwoff = (((bk4 >> 3) ^ ((bn >> 2) & 3)) << 3) + (bk4 & 7);
  const float* wqp = wq + (size_t)(n0 + bn) * CDIM + bk4;

  const int rq = (quad ^ (ml >> 2)) << 3;   // fragment read chunk offset (hw)

  f32x4 acc[4][4] = {};
  f32x4 va[4]; f32x4 vb[4];
  #pragma unroll
  for (int p = 0; p < 4; ++p) va[p] = *(const f32x4*)(apk + (size_t)p * TOKS_PER_B);
  #pragma unroll
  for (int p = 0; p < 4; ++p) vb[p] = *(const f32x4*)(wqp + (size_t)p * 32 * CDIM);

  for (int ks = 0; ks < 12; ++ks) {
    // cvt + LDS write (consumes va/vb)
    #pragma unroll
    for (int t = 0; t < 4; ++t) {
      uint2 u;
      u.x = cvt_pk(va[0][t], va[1][t]);
      u.y = cvt_pk(va[2][t], va[3][t]);
      *(uint2*)&As[(atok + t) ^ aswr][awoff] = u;
    }
    #pragma unroll
    for (int p = 0; p < 4; ++p) {
      uint2 u;
      u.x = cvt_pk(vb[p][0], vb[p][1]);
      u.y = cvt_pk(vb[p][2], vb[p][3]);
      *(uint2*)&Bs[(bn + 32 * p) ^ bswr][bwoff] = u;
    }
    __syncthreads();
    // prefetch next tile into the (now-free) staging regs; latency hides under MFMA
    if (ks < 11) {
      apk += (size_t)32 * TOKS_PER_B;
      wqp += 32;
      #pragma unroll
      for (int p = 0; p < 4; ++p) va[p] = *(const f32x4*)(apk + (size_t)p * TOKS_PER_B);
      #pragma unroll
      for (int p = 0; p < 4; ++p) vb[p] = *(const f32x4*)(wqp + (size_t)p * 32 * CDIM);
    }
    s16x8 af[4], bf[4];
    #pragma unroll
    for (int mi = 0; mi < 4; ++mi)
      af[mi] = __builtin_bit_cast(s16x8, *(const u16x8*)&As[(m_base + mi * 16 + ml) ^ (mi & 1)][rq]);
    #pragma unroll
    for (int ni = 0; ni < 4; ++ni)
      bf[ni] = __builtin_bit_cast(s16x8, *(const u16x8*)&Bs[(n_base + ni * 16 + ml) ^ (ni & 1)][rq]);
    #pragma unroll
    for (int mi = 0; mi < 4; ++mi)
      #pragma unroll
      for (int ni = 0; ni < 4; ++ni)
        acc[mi][ni] = __builtin_amdgcn_mfma_f32_16x16x32_bf16(af[mi], bf[ni], acc[mi][ni], 0, 0, 0);
    __syncthreads();
  }

  // ---- epilogue: scatter into blocked per-(window,head) layout
  int isV_[4]; size_t coff_[4]; float bv_[4];
  #pragma unroll
  for (int ni = 0; ni < 4; ++ni) {
    const int colb = n0 + n_base + ni * 16;           // + ml
    const int sel  = colb / 384;
    const int hd   = (colb - sel * 384) / 96;
    const int db   = colb - sel * 384 - hd * 96;      // + ml, never wraps 96 (16 | colb)
    bv_[ni]  = bias[colb + ml];
    isV_[ni] = (sel == 2);
    coff_[ni] = (size_t)hd * REG_HW +
                (isV_[ni] ? (size_t)VTOFF + (size_t)(db + ml) * 64
                          : (size_t)sel * 4704 + (size_t)(db + ml));
  }
  const unsigned tl00 = (unsigned)(mb * 128 + m_base + quad * 4);
  #pragma unroll
  for (int mi = 0; mi < 4; ++mi) {
    #pragma unroll
    for (int r = 0; r < 4; ++r) {
      const unsigned tl = tl00 + mi * 16 + r;         // chunk-relative token
      const unsigned rl = tl / 224;                   // chunk-local image row
      const unsigned cc = tl - rl * 224;
      const unsigned wr = rl / 7, pr = rl - wr * 7;
      const unsigned wc = cc / 7, pc = cc - wc * 7;
      const size_t   wbase = (size_t)(wr * 32 + wc) * 4 * REG_HW;
      const unsigned pos = pr * 7 + pc;
      #pragma unroll
      for (int ni = 0; ni < 4; ++ni) {
        const unsigned short val = f2bf(acc[mi][ni][r] + bv_[ni]);
        ws[wbase + coff_[ni] + (isV_[ni] ? (size_t)pos : (size_t)pos * 96)] = val;
      }
    }
  }
}

// ---------------- K2: per (window, head) attention, one wave, 9.8 KB LDS ----------------
// grid = (windows_in_chunk, 4 heads), block = 64.  All Q/K/Vt fragments straight from the
// dense per-(win,head) region; only P (bf16 [64][72]) and the O restage (f32 [49][50], two
// 48-channel passes) live in LDS, sharing one 9800 B buffer (single wave -> in-order LDS,
// all P reads complete before O overwrites).
__global__ __launch_bounds__(64) void win_attn(
    const unsigned short* __restrict__ ws, float* __restrict__ out, int win_base) {
  __shared__ float shraw[2450];             // 9800 B union
  unsigned short* P = (unsigned short*)shraw;
  float* O = shraw;
  const int lane = threadIdx.x;
  const int ml = lane & 15, quad = lane >> 4;
  const int w = blockIdx.x, head = blockIdx.y;
  const unsigned short* R = ws + (size_t)(w * 4 + head) * REG_HW;

  const int gwin = win_base + w;
  const int b = gwin >> 10, hw_ = (gwin >> 5) & 31, ww = gwin & 31;

  const s16x8 zf = {0, 0, 0, 0, 0, 0, 0, 0};

  // ---- S = Q K^T  (64x64 padded; rows/cols >=49 zero)
  f32x4 sa[4][4] = {};
  #pragma unroll
  for (int ks = 0; ks < 3; ++ks) {
    s16x8 aq[4], bk[4];
    #pragma unroll
    for (int mi = 0; mi < 4; ++mi) {
      const int pos = mi * 16 + ml;
      if (pos < 49) {
        const unsigned short* rp = R + (size_t)pos * 96 + ks * 32 + quad * 8;
        aq[mi] = __builtin_bit_cast(s16x8, *(const u16x8*)rp);
        bk[mi] = __builtin_bit_cast(s16x8, *(const u16x8*)(rp + KOFF));
      } else { aq[mi] = zf; bk[mi] = zf; }
    }
    #pragma unroll
    for (int mi = 0; mi < 4; ++mi)
      #pragma unroll
      for (int ni = 0; ni < 4; ++ni)
        sa[mi][ni] = __builtin_amdgcn_mfma_f32_16x16x32_bf16(aq[mi], bk[ni], sa[mi][ni], 0, 0, 0);
  }

  // ---- softmax over rows (C/D: row = mi*16+quad*4+r, col = ni*16+ml)
  const float scale = 0.10206207261596577f;  // 96^-0.5 folded into exp arg
  #pragma unroll
  for (int mi = 0; mi < 4; ++mi) {
    #pragma unroll
    for (int r = 0; r < 4; ++r) {
      float mx = -3.0e38f;
      #pragma unroll
      for (int ni = 0; ni < 4; ++ni)
        if (ni * 16 + ml < 49) mx = fmaxf(mx, sa[mi][ni][r]);
      mx = fmaxf(mx, __shfl_xor(mx, 1, 16));
      mx = fmaxf(mx, __shfl_xor(mx, 2, 16));
      mx = fmaxf(mx, __shfl_xor(mx, 4, 16));
      mx = fmaxf(mx, __shfl_xor(mx, 8, 16));
      float e[4], sum = 0.f;
      #pragma unroll
      for (int ni = 0; ni < 4; ++ni) {
        e[ni] = (ni * 16 + ml < 49) ? __expf((sa[mi][ni][r] - mx) * scale) : 0.f;
        sum += e[ni];
      }
      sum += __shfl_xor(sum, 1, 16);
      sum += __shfl_xor(sum, 2, 16);
      sum += __shfl_xor(sum, 4, 16);
      sum += __shfl_xor(sum, 8, 16);
      const float inv = 1.0f / sum;
      const int row = mi * 16 + quad * 4 + r;
      #pragma unroll
      for (int ni = 0; ni < 4; ++ni)
        P[row * 72 + ni * 16 + ml] = f2bf(e[ni] * inv);   // A-operand layout for PV
    }
  }

  // ---- P A-fragments (all P reads done BEFORE O overwrites the buffer)
  s16x8 ap[2][4];
  #pragma unroll
  for (int ks = 0; ks < 2; ++ks)
    #pragma unroll
    for (int mi = 0; mi < 4; ++mi)
      ap[ks][mi] = __builtin_bit_cast(s16x8, *(const u16x8*)&P[(mi * 16 + ml) * 72 + ks * 32 + quad * 8]);

  const unsigned short* Vt = R + VTOFF;
  const size_t obase = ((size_t)(b * CDIM + head * 96) * 224 + (size_t)hw_ * 7) * 224 + ww * 7;

  // ---- O = P V in two 48-channel halves (oa[4][3] keeps VGPR low)
  #pragma unroll
  for (int hh = 0; hh < 2; ++hh) {
    f32x4 oa[4][3] = {};
    #pragma unroll
    for (int ks = 0; ks < 2; ++ks) {
      s16x8 bv[3];
      #pragma unroll
      for (int ni = 0; ni < 3; ++ni)
        bv[ni] = __builtin_bit_cast(s16x8,
            *(const u16x8*)(Vt + (size_t)(hh * 48 + ni * 16 + ml) * 64 + ks * 32 + quad * 8));
      #pragma unroll
      for (int mi = 0; mi < 4; ++mi)
        #pragma unroll
        for (int ni = 0; ni < 3; ++ni)
          oa[mi][ni] = __builtin_amdgcn_mfma_f32_16x16x32_bf16(ap[ks][mi], bv[ni], oa[mi][ni], 0, 0, 0);
    }
    // restage (single wave: LDS in-order, no barrier needed)
    #pragma unroll
    for (int mi = 0; mi < 4; ++mi)
      #pragma unroll
      for (int r = 0; r < 4; ++r) {
        const int row = mi * 16 + quad * 4 + r;
        if (row < 49) {
          #pragma unroll
          for (int ni = 0; ni < 3; ++ni)
            O[row * 50 + ni * 16 + ml] = oa[mi][ni][r];
        }
      }
    for (int idx = lane; idx < 49 * 48; idx += 64) {
      const int dd = idx / 49, pos = idx - dd * 49;
      const int rr2 = pos / 7, cc2 = pos - rr2 * 7;
      out[obase + ((size_t)(hh * 48 + dd) * 224 + rr2) * 224 + cc2] = O[pos * 50 + dd];
    }
  }
}

extern "C" void kernel_launch(void* const* d_in, const int* in_sizes, int n_in,
                              void* d_out, int out_size, void* d_ws, size_t ws_size,
                              hipStream_t stream) {
  const float* x    = (const float*)d_in[0];
  const float* wq   = (const float*)d_in[1];
  const float* bias = (const float*)d_in[2];
  float* out = (float*)d_out;
  unsigned short* ws = (unsigned short*)d_ws;

  // chunk unit = 4 window-rows = 6272 tokens = 128 windows; region bytes/unit:
  const long long UNIT_TOK = 6272;
  const size_t UNIT_BYTES = (size_t)128 * 4 * REG_HW * 2;   // 15.93 MB
  int upc = (int)(ws_size / UNIT_BYTES);
  if (upc < 1) upc = 1;
  if (upc > 64) upc = 64;

  // zero Vt pos-padding once; chunk iterations reuse the same region addresses
  {
    const int total = upc * 128 * 4 * 96;
    pad_zero<<<dim3((total + 255) / 256), dim3(256), 0, stream>>>(ws, total);
  }

  for (int u0 = 0; u0 < 64; u0 += upc) {
    const int units = (u0 + upc <= 64) ? upc : (64 - u0);
    const long long t_base = (long long)u0 * UNIT_TOK;
    const int toks = units * (int)UNIT_TOK;
    const int nwg = 9 * (toks / 128);
    qkv_gemm<<<dim3(nwg), dim3(256), 0, stream>>>(x, wq, bias, ws, t_base, nwg);
    dim3 g2(units * 128, 4);
    win_attn<<<g2, dim3(64), 0, stream>>>(ws, out, u0 * 128);
  }
}